// Round 12
// baseline (522.450 us; speedup 1.0000x reference)
//
#include <hip/hip_runtime.h>
#include <hip/hip_bf16.h>
#include <math.h>

// Problem constants
#define NROWS 131072      // 32*64*64
#define DDIM  64
#define KCODE 1024
#define TAU_B 0.008f      // split-bf16 dist err <= ~2e-3; 4x margin

// d_out layout (float elements, return order)
#define OFF_Q    0L
#define OFF_LOSS 8388608L
#define OFF_PERP 8388609L
#define OFF_ENC  8388610L                 // only 8B-aligned (base ≡ 2 mod 4 floats)
#define OFF_IDX  (OFF_ENC + 134217728L)   // 142606338
#define OFF_DIST (OFF_IDX + 131072L)      // 142737410 — only 8B-aligned

// ws layout (float elements)
#define WS_ENORM 0L          // 1024 f
#define WS_ET    1024L       // 65536 f   eT[k][d]
#define WS_EBPH  66560L      // 32768 f = 65536 ushort (packed B hi)
#define WS_EBPL  99328L      // 32768 f
#define WS_CNT   263168L     // 1024 int
#define WS_PART  395268L     // 8192 f

typedef short bf16x8 __attribute__((ext_vector_type(8)));
typedef float f32x4  __attribute__((ext_vector_type(4)));
typedef float f32x2  __attribute__((ext_vector_type(2)));
typedef _Float16 f16x4v __attribute__((ext_vector_type(4)));
typedef float f32x4u __attribute__((ext_vector_type(4), aligned(8)));  // 8B-aligned dwordx4

__device__ inline unsigned short f2bf(float f) {
    unsigned u = __float_as_uint(f);
    unsigned r = (u + 0x7fffu + ((u >> 16) & 1u)) >> 16;
    return (unsigned short)r;
}
__device__ inline float bf2f(unsigned short h) {
    return __uint_as_float(((unsigned)h) << 16);
}
// per-wave 16x256 f16 chunk swizzle: XOR f16-idx bits 4-5 with row-group
// (bits 10-11). Keeps 4-f16 groups contiguous and 8B alignment; spreads the
// 4 fragment row-groups across bank quadrants (write ~conflict-free).
__device__ inline int cswz(int i) { return i ^ (((i >> 10) & 3) << 4); }

// ---------------- k1a: e-norms (f32), eT for gather, zero cnt ----------------
__global__ __launch_bounds__(256) void k1a_prep(const float* __restrict__ e,
                                                float* __restrict__ enorm,
                                                float* __restrict__ eT,
                                                int* __restrict__ cnt) {
    int k = blockIdx.x * 256 + threadIdx.x;   // grid=4 -> k in [0,1024)
    float s = 0.f;
    #pragma unroll 8
    for (int d = 0; d < DDIM; ++d) {
        float v = e[(size_t)d * KCODE + k];
        s = fmaf(v, v, s);
        eT[(size_t)k * DDIM + d] = v;
    }
    enorm[k] = s;
    cnt[k] = 0;
}

// ---------------- k1b: pack e into MFMA-B fragment layout, hi/lo bf16 ----------------
__global__ __launch_bounds__(128) void k1b_pack(const float* __restrict__ e,
                                                unsigned short* __restrict__ ebph,
                                                unsigned short* __restrict__ ebpl) {
    const int gct = blockIdx.x;          // 0..63
    const int ks  = threadIdx.x >> 6;    // 0..1
    const int l   = threadIdx.x & 63;
    const int col = (gct << 4) | (l & 15);
    const int kb  = (ks << 5) + ((l >> 4) << 3);
    const size_t ob = ((size_t)((gct << 1) | ks) * 64 + l) * 8;
    #pragma unroll
    for (int j = 0; j < 8; ++j) {
        float f = e[(size_t)(kb + j) * KCODE + col];
        unsigned short h = f2bf(f);
        float lo = f - bf2f(h);
        ebph[ob + j] = h;
        ebpl[ob + j] = f2bf(lo);
    }
}

// ---------------- kA: wave-autonomous fused kernel ----------------
// Block = 4 independent waves; each wave owns 16 rows x all 1024 codes.
// Per wave: stage own x -> frags; 4 chunks x 16 cts {enc-zero interleave,
// MFMA, min-chain, fragment->LDS}; per-chunk own-region dist sweep (1KB-
// contiguous stores, lgkmcnt only); wave-local argmin + f64 refine;
// s_waitcnt vmcnt(0); epilogue (one-hot fixup, outq, idx, hist, partial).
// ZERO block barriers -> waves self-stagger, write pipe stays busy.
__global__ __launch_bounds__(256, 4) void kA_dist(const float* __restrict__ x,
                                                  const float* __restrict__ e,
                                                  const unsigned short* __restrict__ ebph,
                                                  const unsigned short* __restrict__ ebpl,
                                                  const float* __restrict__ enorm,
                                                  const float* __restrict__ eT,
                                                  float* __restrict__ dist,
                                                  float* __restrict__ enc,
                                                  float* __restrict__ outq,
                                                  float* __restrict__ outidx,
                                                  int* __restrict__ cnt,
                                                  float* __restrict__ partials) {
    __shared__ __align__(16) _Float16 dtH[4][4096];  // 8KB/wave: union(xh+xl, dist chunk)
    __shared__ float xnS[4][16];
    __shared__ float psS[4][16];
    __shared__ int   sidxS[4][16];
    __shared__ int   flagsS[4];

    const int tid  = threadIdx.x;
    const int lane = tid & 63;
    const int w    = tid >> 6;
    const int grow0 = blockIdx.x * 64 + w * 16;      // this wave's first row
    float* encw = enc + ((size_t)grow0 << 10);       // 64KB region, base ≡ 2 mod 4
    short* xh = (short*)&dtH[w][0];                  // first 2KB of union
    short* xl = (short*)&dtH[w][1024];               // next 2KB

    if (lane == 0) flagsS[w] = 0;

    // ---- stage own 16 rows: f32 -> (hi,lo) bf16; row norms via 16-lane shuffle
    {
        const float* xrow = x + ((size_t)grow0 << 6);
        #pragma unroll
        for (int q = 0; q < 4; ++q) {
            float4 v = ((const float4*)xrow)[(q << 6) + lane];
            const int row = (q << 2) + (lane >> 4), col = (lane & 15) << 2;
            float fv[4] = {v.x, v.y, v.z, v.w};
            short hv[4], lv[4];
            #pragma unroll
            for (int c = 0; c < 4; ++c) {
                unsigned short hh = f2bf(fv[c]);
                hv[c] = (short)hh;
                lv[c] = (short)f2bf(fv[c] - bf2f(hh));
            }
            *(short4*)&xh[row * 64 + col] = make_short4(hv[0], hv[1], hv[2], hv[3]);
            *(short4*)&xl[row * 64 + col] = make_short4(lv[0], lv[1], lv[2], lv[3]);
            float s4 = fmaf(v.x, v.x, fmaf(v.y, v.y, fmaf(v.z, v.z, v.w * v.w)));
            #pragma unroll
            for (int m = 1; m < 16; m <<= 1) s4 += __shfl_xor(s4, m);
            if ((lane & 15) == 0) xnS[w][row] = s4;
        }
    }

    // ---- A fragments from own staged rows (same-wave LDS RAW; lgkmcnt auto)
    const int arow = lane & 15, akb = (lane >> 4) << 3;
    bf16x8 ah0 = *(const bf16x8*)&xh[arow * 64 + akb];
    bf16x8 ah1 = *(const bf16x8*)&xh[arow * 64 + 32 + akb];
    bf16x8 al0 = *(const bf16x8*)&xl[arow * 64 + akb];
    bf16x8 al1 = *(const bf16x8*)&xl[arow * 64 + 32 + akb];

    const int wr = (lane >> 4) << 2;      // fragment row block (rows wr..wr+3)
    float xnv[4];
    #pragma unroll
    for (int r = 0; r < 4; ++r) xnv[r] = xnS[w][wr + r];

    float m1[4], m2[4];
    int   i1[4];
    #pragma unroll
    for (int r = 0; r < 4; ++r) { m1[r] = 3.4e38f; m2[r] = 3.4e38f; i1[r] = 1 << 30; }

    const f32x4 z4 = {0.f, 0.f, 0.f, 0.f};

    // ---- main loop: 4 chunks x 16 cts, per-chunk own-region sweep
    for (int ch = 0; ch < 4; ++ch) {
        #pragma unroll 4
        for (int cc = 0; cc < 16; ++cc) {
            const int ct = (ch << 4) | cc;
            const size_t bo = ((size_t)(ct << 1) * 64 + lane) * 8;
            bf16x8 bh0 = *(const bf16x8*)(ebph + bo);
            bf16x8 bh1 = *(const bf16x8*)(ebph + bo + 512);
            bf16x8 bl0 = *(const bf16x8*)(ebpl + bo);
            bf16x8 bl1 = *(const bf16x8*)(ebpl + bo + 512);

            // enc zero-stream interleave: 1KB per wave per ct
            {
                const int s = (ct << 6) + lane;            // 0..4095
                if (s < 4095) {
                    *(f32x4*)(encw + 2 + (s << 2)) = z4;
                } else {                                   // last: head + tail f32x2
                    *(f32x2*)(encw)         = (f32x2){0.f, 0.f};
                    *(f32x2*)(encw + 16382) = (f32x2){0.f, 0.f};
                }
            }
            const float env = enorm[(ct << 4) + (lane & 15)];   // L2-hot

            f32x4 d = {0.f, 0.f, 0.f, 0.f};
            d = __builtin_amdgcn_mfma_f32_16x16x32_bf16(ah0, bh0, d, 0, 0, 0);
            d = __builtin_amdgcn_mfma_f32_16x16x32_bf16(ah1, bh1, d, 0, 0, 0);
            d = __builtin_amdgcn_mfma_f32_16x16x32_bf16(ah0, bl0, d, 0, 0, 0);
            d = __builtin_amdgcn_mfma_f32_16x16x32_bf16(ah1, bl1, d, 0, 0, 0);
            d = __builtin_amdgcn_mfma_f32_16x16x32_bf16(al0, bh0, d, 0, 0, 0);
            d = __builtin_amdgcn_mfma_f32_16x16x32_bf16(al1, bh1, d, 0, 0, 0);

            const int col = (ct << 4) | (lane & 15);
            #pragma unroll
            for (int r = 0; r < 4; ++r) {
                float o = fmaf(-2.f, d[r], xnv[r] + env);
                if (o < m1[r]) { m2[r] = m1[r]; m1[r] = o; i1[r] = col; }
                else if (o < m2[r]) m2[r] = o;
                const int fl = ((wr + r) << 8) + (cc << 4) + (lane & 15);
                dtH[w][cswz(fl)] = (_Float16)o;
            }
        }
        // own-region dist sweep: 16 rows x 256 cols, 1KB contiguous per inst.
        // Reads only this wave's writes -> lgkmcnt ordering, NO barrier.
        #pragma unroll
        for (int r = 0; r < 16; ++r) {
            f16x4v h = *(const f16x4v*)&dtH[w][cswz((r << 8) + (lane << 2))];
            f32x4u v = {(float)h[0], (float)h[1], (float)h[2], (float)h[3]};
            *(f32x4u*)(dist + ((size_t)(grow0 + r) << 10) + (ch << 8) + (lane << 2)) = v;
        }
    }

    // ---- wave-local argmin merge over the 16 lanes sharing each row group
    #pragma unroll
    for (int m = 1; m < 16; m <<= 1) {
        #pragma unroll
        for (int r = 0; r < 4; ++r) {
            float om1 = __shfl_xor(m1[r], m);
            int   oi1 = __shfl_xor(i1[r], m);
            float om2 = __shfl_xor(m2[r], m);
            if (om1 < m1[r] || (om1 == m1[r] && oi1 < i1[r])) {
                m2[r] = fminf(m1[r], om2); m1[r] = om1; i1[r] = oi1;
            } else {
                m2[r] = fminf(m2[r], om1);
            }
        }
    }
    if ((lane & 15) == 0) {
        int nib = 0;
        #pragma unroll
        for (int r = 0; r < 4; ++r) {
            sidxS[w][wr + r] = i1[r];
            psS[w][wr + r]   = m1[r];
            if (m2[r] - m1[r] < TAU_B) nib |= 1 << r;
        }
        if (nib) atomicOr(&flagsS[w], nib << wr);
    }

    // ---- wave-local f64 refinement of near-tie rows (rare)
    int fmask = flagsS[w];
    while (fmask) {
        const int r = __ffs(fmask) - 1;
        fmask &= fmask - 1;
        const float xv = x[((size_t)(grow0 + r) << 6) + lane];
        double dd[16];
        #pragma unroll
        for (int kk = 0; kk < 16; ++kk) dd[kk] = 0.0;
        for (int di = 0; di < DDIM; ++di) {
            const double xd = (double)__shfl(xv, di);
            const float* ep = e + ((size_t)di << 10) + (lane << 4);
            #pragma unroll
            for (int g = 0; g < 4; ++g) {
                f32x4 ev = *(const f32x4*)(ep + (g << 2));
                #pragma unroll
                for (int c = 0; c < 4; ++c) {
                    double t = xd - (double)ev[c];
                    dd[(g << 2) + c] = fma(t, t, dd[(g << 2) + c]);
                }
            }
        }
        double best = dd[0];
        int bidx = lane << 4;
        #pragma unroll
        for (int kk = 1; kk < 16; ++kk)
            if (dd[kk] < best) { best = dd[kk]; bidx = (lane << 4) + kk; }
        #pragma unroll
        for (int m = 1; m < 64; m <<= 1) {
            double ob = __shfl_xor(best, m);
            int    oi = __shfl_xor(bidx, m);
            if (ob < best || (ob == best && oi < bidx)) { best = ob; bidx = oi; }
        }
        if (lane == 0) { sidxS[w][r] = bidx; psS[w][r] = (float)best; }
    }

    // ---- ensure enc zeros landed before the one-hot fixup (same-wave, vmcnt only)
    __builtin_amdgcn_s_waitcnt(0x3f70);   // vmcnt(0)

    // ---- epilogue (all wave-local)
    if (lane < 16) {
        const int idx = sidxS[w][lane];
        encw[((size_t)lane << 10) + idx] = 1.0f;
        outidx[grow0 + lane] = (float)idx;
        atomicAdd(cnt + idx, 1);
    }
    #pragma unroll
    for (int q = 0; q < 4; ++q) {
        const int r = (q << 2) + (lane >> 4);
        const int idx = sidxS[w][r];
        f32x4 ev = *(const f32x4*)(eT + ((size_t)idx << 6) + ((lane & 15) << 2));
        *((f32x4*)(outq + ((size_t)(grow0 + r) << 6)) + (lane & 15)) = ev;
    }
    if (lane == 0) {
        float s = 0.f;
        #pragma unroll
        for (int j = 0; j < 16; ++j) s += psS[w][j];
        partials[(blockIdx.x << 2) + w] = s;
    }
}

// ---------------- k6: loss + perplexity ----------------
__global__ __launch_bounds__(256) void k6_scalar(const float* __restrict__ partials,
                                                 const int* __restrict__ cnt,
                                                 float* __restrict__ outloss,
                                                 float* __restrict__ outperp) {
    __shared__ double sd[256];
    const int tid = threadIdx.x;
    double s = 0.0;
    for (int i = tid; i < 8192; i += 256) s += (double)partials[i];
    sd[tid] = s;
    __syncthreads();
    for (int st = 128; st > 0; st >>= 1) {
        if (tid < st) sd[tid] += sd[tid + st];
        __syncthreads();
    }
    const double total = sd[0];
    __syncthreads();
    double h = 0.0;
    for (int k = tid; k < KCODE; k += 256) {
        double p = (double)cnt[k] / (double)NROWS;
        h -= p * log(p + 1e-10);
    }
    sd[tid] = h;
    __syncthreads();
    for (int st = 128; st > 0; st >>= 1) {
        if (tid < st) sd[tid] += sd[tid + st];
        __syncthreads();
    }
    if (tid == 0) {
        *outloss = (float)(total * 1.25 / (double)((long)NROWS * DDIM));
        *outperp = (float)exp(sd[0]);
    }
}

extern "C" void kernel_launch(void* const* d_in, const int* in_sizes, int n_in,
                              void* d_out, int out_size, void* d_ws, size_t ws_size,
                              hipStream_t stream) {
    const float* x = (const float*)d_in[0];       // [131072, 64]
    const float* e = (const float*)d_in[1];       // [64, 1024]
    float* out = (float*)d_out;

    float* ws_f = (float*)d_ws;
    float* enorm   = ws_f + WS_ENORM;
    float* eT      = ws_f + WS_ET;
    unsigned short* ebph = (unsigned short*)(ws_f + WS_EBPH);
    unsigned short* ebpl = (unsigned short*)(ws_f + WS_EBPL);
    int*   cnt     = (int*)(ws_f + WS_CNT);
    float* partials= ws_f + WS_PART;

    float* outq    = out + OFF_Q;
    float* outloss = out + OFF_LOSS;
    float* outperp = out + OFF_PERP;
    float* enc     = out + OFF_ENC;
    float* outidx  = out + OFF_IDX;
    float* dist    = out + OFF_DIST;

    hipLaunchKernelGGL(k1a_prep, dim3(4),    dim3(256), 0, stream, e, enorm, eT, cnt);
    hipLaunchKernelGGL(k1b_pack, dim3(64),   dim3(128), 0, stream, e, ebph, ebpl);
    hipLaunchKernelGGL(kA_dist,  dim3(2048), dim3(256), 0, stream, x, e, ebph, ebpl, enorm,
                       eT, dist, enc, outq, outidx, cnt, partials);
    hipLaunchKernelGGL(k6_scalar,dim3(1),    dim3(256), 0, stream, partials, cnt, outloss, outperp);
}

// Round 13
// 320.425 us; speedup vs baseline: 1.6305x; 1.6305x over previous
//
#include <hip/hip_runtime.h>
#include <hip/hip_bf16.h>
#include <math.h>

// Problem constants
#define NROWS 131072      // 32*64*64
#define DDIM  64
#define KCODE 1024
#define TAU_B 0.008f      // split-bf16 dist err <= ~2e-3; 4x margin

// d_out layout (float elements, return order)
#define OFF_Q    0L
#define OFF_LOSS 8388608L
#define OFF_PERP 8388609L
#define OFF_ENC  8388610L                 // only 8B-aligned (base ≡ 2 mod 4 floats)
#define OFF_IDX  (OFF_ENC + 134217728L)   // 142606338
#define OFF_DIST (OFF_IDX + 131072L)      // 142737410 — only 8B-aligned

// ws layout (float elements)
#define WS_ENORM 0L          // 1024 f
#define WS_ET    1024L       // 65536 f   eT[k][d]
#define WS_EBPH  66560L      // 32768 f = 65536 ushort (packed B hi)
#define WS_EBPL  99328L      // 32768 f
#define WS_CNT   263168L     // 1024 int
#define WS_PART  395268L     // 8192 f

typedef short bf16x8 __attribute__((ext_vector_type(8)));
typedef float f32x4  __attribute__((ext_vector_type(4)));
typedef float f32x2  __attribute__((ext_vector_type(2)));
typedef _Float16 f16x4v __attribute__((ext_vector_type(4)));
typedef _Float16 f16x2v __attribute__((ext_vector_type(2)));

__device__ inline unsigned short f2bf(float f) {
    unsigned u = __float_as_uint(f);
    unsigned r = (u + 0x7fffu + ((u >> 16) & 1u)) >> 16;
    return (unsigned short)r;
}
__device__ inline float bf2f(unsigned short h) {
    return __uint_as_float(((unsigned)h) << 16);
}
// f16 dist-tile swizzle: XOR bits 3,4 by row-group (bits 12,13).
// Preserves runs within 8-f16 blocks (all our reads are 4-runs at ≡0 mod 4
// or 2-runs at even ≡4/6 mod 8), and 8B alignment. Bijective.
__device__ inline int dswz16(int i) { return i ^ (((i >> 12) & 3) << 3); }

// lgkmcnt-only barrier: LDS visibility without draining the vmem store queue
// (enc/dist stores stay in flight across the phase boundary — T4 style).
__device__ inline void lds_barrier() {
    asm volatile("s_waitcnt lgkmcnt(0)" ::: "memory");
    __builtin_amdgcn_s_barrier();
    __builtin_amdgcn_sched_barrier(0);
}

// ---------------- k1a: e-norms (f32), eT for gather, zero cnt ----------------
__global__ __launch_bounds__(256) void k1a_prep(const float* __restrict__ e,
                                                float* __restrict__ enorm,
                                                float* __restrict__ eT,
                                                int* __restrict__ cnt) {
    int k = blockIdx.x * 256 + threadIdx.x;   // grid=4 -> k in [0,1024)
    float s = 0.f;
    #pragma unroll 8
    for (int d = 0; d < DDIM; ++d) {
        float v = e[(size_t)d * KCODE + k];
        s = fmaf(v, v, s);
        eT[(size_t)k * DDIM + d] = v;
    }
    enorm[k] = s;
    cnt[k] = 0;
}

// ---------------- k1b: pack e into MFMA-B fragment layout, hi/lo bf16 ----------------
__global__ __launch_bounds__(128) void k1b_pack(const float* __restrict__ e,
                                                unsigned short* __restrict__ ebph,
                                                unsigned short* __restrict__ ebpl) {
    const int gct = blockIdx.x;          // 0..63
    const int ks  = threadIdx.x >> 6;    // 0..1
    const int l   = threadIdx.x & 63;
    const int col = (gct << 4) | (l & 15);
    const int kb  = (ks << 5) + ((l >> 4) << 3);
    const size_t ob = ((size_t)((gct << 1) | ks) * 64 + l) * 8;
    #pragma unroll
    for (int j = 0; j < 8; ++j) {
        float f = e[(size_t)(kb + j) * KCODE + col];
        unsigned short h = f2bf(f);
        float lo = f - bf2f(h);
        ebph[ob + j] = h;
        ebpl[ob + j] = f2bf(lo);
    }
}

// ---------------- kA: fused, software-pipelined ----------------
// col-tile map gct=(c<<2)|w: after c=0..7 the block's cols 0..511 are complete
// -> their dist stores interleave into c=8..15 alongside the enc zero-stream.
// Tail sweep covers cols 512..1023. lgkm-only barriers keep stores in flight.
__global__ __launch_bounds__(256, 4) void kA_fused(const float* __restrict__ x,
                                                   const float* __restrict__ e,
                                                   const unsigned short* __restrict__ ebph,
                                                   const unsigned short* __restrict__ ebpl,
                                                   const float* __restrict__ enorm,
                                                   const float* __restrict__ eT,
                                                   float* __restrict__ dist,
                                                   float* __restrict__ enc,
                                                   float* __restrict__ outq,
                                                   float* __restrict__ outidx,
                                                   int* __restrict__ cnt,
                                                   float* __restrict__ partials) {
    __shared__ __align__(16) _Float16 dtH[16384];  // dist tile (f16), index = flat-2, swizzled
    __shared__ float hd[2];                        // flats 0,1 (row0 col0,1)
    __shared__ short xh[16 * 64];
    __shared__ short xl[16 * 64];
    __shared__ float xn[16];
    __shared__ float wm1[4][16], wm2[4][16];
    __shared__ int   wi1[4][16];
    __shared__ float ps[16];
    __shared__ int   sidx[16];
    __shared__ int   nearmask;
    __shared__ float xsh[DDIM];
    __shared__ double wbv[4];
    __shared__ int    wbi[4];

    const int tid  = threadIdx.x;
    const int lane = tid & 63;
    const int w    = tid >> 6;
    const int rowbase = blockIdx.x * 16;
    float* encw  = enc  + ((size_t)blockIdx.x << 14);   // 64KB region, ≡2 mod 4
    float* dbase = dist + ((size_t)rowbase << 10);      // ≡2 mod 4

    // ---- stage x tile: f32 -> (hi,lo) bf16 in LDS; row norms via shuffle
    {
        if (tid == 0) nearmask = 0;
        float4 v = ((const float4*)(x + (size_t)rowbase * DDIM))[tid];
        int fi = tid * 4, r = fi >> 6, c = fi & 63;
        float fv[4] = {v.x, v.y, v.z, v.w};
        short hv[4], lv[4];
        #pragma unroll
        for (int q = 0; q < 4; ++q) {
            unsigned short hh = f2bf(fv[q]);
            hv[q] = (short)hh;
            lv[q] = (short)f2bf(fv[q] - bf2f(hh));
        }
        *(short4*)&xh[r * 64 + c] = make_short4(hv[0], hv[1], hv[2], hv[3]);
        *(short4*)&xl[r * 64 + c] = make_short4(lv[0], lv[1], lv[2], lv[3]);
        float s4 = fmaf(v.x, v.x, fmaf(v.y, v.y, fmaf(v.z, v.z, v.w * v.w)));
        #pragma unroll
        for (int m = 1; m < 16; m <<= 1) s4 += __shfl_xor(s4, m);
        if ((lane & 15) == 0) xn[r] = s4;
    }
    __syncthreads();

    // ---- A fragments: lane l -> row=l&15, k=(l>>4)*8+j (+32 for second K-step)
    const int arow = lane & 15, akb = (lane >> 4) << 3;
    bf16x8 ah0 = *(const bf16x8*)&xh[arow * 64 + akb];
    bf16x8 ah1 = *(const bf16x8*)&xh[arow * 64 + 32 + akb];
    bf16x8 al0 = *(const bf16x8*)&xl[arow * 64 + akb];
    bf16x8 al1 = *(const bf16x8*)&xl[arow * 64 + 32 + akb];

    const int wr = (lane >> 4) << 2;       // C-fragment row block (rows wr..wr+3)
    float xnv[4];
    #pragma unroll
    for (int r = 0; r < 4; ++r) xnv[r] = xn[wr + r];
    float env[16];
    #pragma unroll
    for (int c = 0; c < 16; ++c)
        env[c] = enorm[(((c << 2) | w) << 4) + (lane & 15)];   // L2-hot

    float m1[4], m2[4];
    int   i1[4];
    #pragma unroll
    for (int r = 0; r < 4; ++r) { m1[r] = 3.4e38f; m2[r] = 3.4e38f; i1[r] = 1 << 30; }

    const f32x4 z4 = {0.f, 0.f, 0.f, 0.f};

    // ---- phase 1: cts with gct in [0,32) -> cols 0..511; enc interleaved
    #pragma unroll 4
    for (int c = 0; c < 8; ++c) {
        const int gct = (c << 2) | w;
        {
            const int s = (c << 8) + tid;
            if (s < 4095) *(f32x4*)(encw + 2 + (s << 2)) = z4;
            else {
                *(f32x2*)(encw)         = (f32x2){0.f, 0.f};
                *(f32x2*)(encw + 16382) = (f32x2){0.f, 0.f};
            }
        }
        const size_t bo = ((size_t)(gct << 1) * 64 + lane) * 8;
        bf16x8 bh0 = *(const bf16x8*)(ebph + bo);
        bf16x8 bh1 = *(const bf16x8*)(ebph + bo + 512);
        bf16x8 bl0 = *(const bf16x8*)(ebpl + bo);
        bf16x8 bl1 = *(const bf16x8*)(ebpl + bo + 512);

        f32x4 d = {0.f, 0.f, 0.f, 0.f};
        d = __builtin_amdgcn_mfma_f32_16x16x32_bf16(ah0, bh0, d, 0, 0, 0);
        d = __builtin_amdgcn_mfma_f32_16x16x32_bf16(ah1, bh1, d, 0, 0, 0);
        d = __builtin_amdgcn_mfma_f32_16x16x32_bf16(ah0, bl0, d, 0, 0, 0);
        d = __builtin_amdgcn_mfma_f32_16x16x32_bf16(ah1, bl1, d, 0, 0, 0);
        d = __builtin_amdgcn_mfma_f32_16x16x32_bf16(al0, bh0, d, 0, 0, 0);
        d = __builtin_amdgcn_mfma_f32_16x16x32_bf16(al1, bh1, d, 0, 0, 0);

        const int col = (gct << 4) | (lane & 15);
        #pragma unroll
        for (int r = 0; r < 4; ++r) {
            float o = fmaf(-2.f, d[r], xnv[r] + env[c]);
            if (o < m1[r]) { m2[r] = m1[r]; m1[r] = o; i1[r] = col; }
            else if (o < m2[r]) m2[r] = o;
            const int fl = ((wr + r) << 10) + col;
            if (fl >= 2) dtH[dswz16(fl - 2)] = (_Float16)o;
            else         hd[fl] = o;
        }
    }

    // phase boundary: LDS visibility only — vmem stores stay in flight
    lds_barrier();

    // ---- phase 2: gct in [32,64) (cols 512..1023) + pipelined sweep of cols 0..511
    #pragma unroll 4
    for (int c = 8; c < 16; ++c) {
        const int gct = (c << 2) | w;
        {
            const int s = (c << 8) + tid;
            if (s < 4095) *(f32x4*)(encw + 2 + (s << 2)) = z4;
            else {
                *(f32x2*)(encw)         = (f32x2){0.f, 0.f};
                *(f32x2*)(encw + 16382) = (f32x2){0.f, 0.f};
            }
        }
        // pipelined first-half dist sweep: one slot per thread per ct
        {
            const int f = ((c - 8) << 8) + tid;       // 0..2047
            const int row = f >> 7, k = f & 127;
            if (k < 127) {
                const int j0 = (row << 10) + (k << 2);          // ≡0 mod 4
                f16x4v h = *(const f16x4v*)&dtH[dswz16(j0)];
                *(f32x4*)(dbase + 2 + j0) =
                    (f32x4){(float)h[0], (float)h[1], (float)h[2], (float)h[3]};
            } else {
                // head: cols 0,1 of row
                float h0, h1;
                if (row == 0) { h0 = hd[0]; h1 = hd[1]; }
                else {
                    f16x2v t = *(const f16x2v*)&dtH[dswz16((row << 10) - 2)];
                    h0 = (float)t[0]; h1 = (float)t[1];
                }
                *(f32x2*)(dbase + (row << 10)) = (f32x2){h0, h1};
                // tail: cols 510,511
                f16x2v t2 = *(const f16x2v*)&dtH[dswz16((row << 10) + 508)];
                *(f32x2*)(dbase + (row << 10) + 510) = (f32x2){(float)t2[0], (float)t2[1]};
            }
        }
        const size_t bo = ((size_t)(gct << 1) * 64 + lane) * 8;
        bf16x8 bh0 = *(const bf16x8*)(ebph + bo);
        bf16x8 bh1 = *(const bf16x8*)(ebph + bo + 512);
        bf16x8 bl0 = *(const bf16x8*)(ebpl + bo);
        bf16x8 bl1 = *(const bf16x8*)(ebpl + bo + 512);

        f32x4 d = {0.f, 0.f, 0.f, 0.f};
        d = __builtin_amdgcn_mfma_f32_16x16x32_bf16(ah0, bh0, d, 0, 0, 0);
        d = __builtin_amdgcn_mfma_f32_16x16x32_bf16(ah1, bh1, d, 0, 0, 0);
        d = __builtin_amdgcn_mfma_f32_16x16x32_bf16(ah0, bl0, d, 0, 0, 0);
        d = __builtin_amdgcn_mfma_f32_16x16x32_bf16(ah1, bl1, d, 0, 0, 0);
        d = __builtin_amdgcn_mfma_f32_16x16x32_bf16(al0, bh0, d, 0, 0, 0);
        d = __builtin_amdgcn_mfma_f32_16x16x32_bf16(al1, bh1, d, 0, 0, 0);

        const int col = (gct << 4) | (lane & 15);
        #pragma unroll
        for (int r = 0; r < 4; ++r) {
            float o = fmaf(-2.f, d[r], xnv[r] + env[c]);
            if (o < m1[r]) { m2[r] = m1[r]; m1[r] = o; i1[r] = col; }
            else if (o < m2[r]) m2[r] = o;
            const int fl = ((wr + r) << 10) + col;          // fl >= 512 here
            dtH[dswz16(fl - 2)] = (_Float16)o;
        }
    }

    // ---- per-wave argmin partials to LDS (before the visibility barrier)
    #pragma unroll
    for (int m = 1; m < 16; m <<= 1) {
        #pragma unroll
        for (int r = 0; r < 4; ++r) {
            float om1 = __shfl_xor(m1[r], m);
            int   oi1 = __shfl_xor(i1[r], m);
            float om2 = __shfl_xor(m2[r], m);
            if (om1 < m1[r] || (om1 == m1[r] && oi1 < i1[r])) {
                m2[r] = fminf(m1[r], om2); m1[r] = om1; i1[r] = oi1;
            } else {
                m2[r] = fminf(m2[r], om1);
            }
        }
    }
    if ((lane & 15) == 0) {
        #pragma unroll
        for (int r = 0; r < 4; ++r) {
            wm1[w][wr + r] = m1[r];
            wm2[w][wr + r] = m2[r];
            wi1[w][wr + r] = i1[r];
        }
    }

    lds_barrier();   // frag writes (cols 512..1023) + wm visible; stores stay in flight

    // ---- tail sweep: cols 512..1023
    #pragma unroll
    for (int it = 0; it < 8; ++it) {
        const int f = (it << 8) + tid;            // 0..2047
        const int row = f >> 7, k = f & 127;
        if (k < 127) {
            const int j0 = (row << 10) + 512 + (k << 2);     // ≡0 mod 4
            f16x4v h = *(const f16x4v*)&dtH[dswz16(j0)];
            *(f32x4*)(dbase + 2 + j0) =
                (f32x4){(float)h[0], (float)h[1], (float)h[2], (float)h[3]};
        } else {
            f16x2v th = *(const f16x2v*)&dtH[dswz16((row << 10) + 510)];
            *(f32x2*)(dbase + (row << 10) + 512) = (f32x2){(float)th[0], (float)th[1]};
            f16x2v tt = *(const f16x2v*)&dtH[dswz16((row << 10) + 1020)];
            *(f32x2*)(dbase + (row << 10) + 1022) = (f32x2){(float)tt[0], (float)tt[1]};
        }
    }

    // ---- block argmin merge (wm already visible)
    if (tid < 16) {
        float bm1 = wm1[0][tid], bm2 = wm2[0][tid];
        int   bi  = wi1[0][tid];
        #pragma unroll
        for (int wv = 1; wv < 4; ++wv) {
            float om1 = wm1[wv][tid], om2 = wm2[wv][tid];
            int   oi  = wi1[wv][tid];
            if (om1 < bm1 || (om1 == bm1 && oi < bi)) {
                bm2 = fminf(bm1, om2); bm1 = om1; bi = oi;
            } else {
                bm2 = fminf(bm2, om1);
            }
        }
        sidx[tid] = bi;
        ps[tid]   = bm1;                    // min-dist == ||x-q||^2 for loss
        if (bm2 - bm1 < TAU_B) atomicOr(&nearmask, 1 << tid);
    }
    __syncthreads();    // full drain: enc/dist landed; nearmask/sidx visible

    // ---- inline f64 refinement of near-tie rows (rare)
    if (nearmask) {
        for (int mrow = nearmask; mrow; mrow &= (mrow - 1)) {
            const int r = __ffs(mrow) - 1;
            if (tid < DDIM) xsh[tid] = x[(size_t)(rowbase + r) * DDIM + tid];
            __syncthreads();
            const int k0 = tid * 4;
            double dd[4] = {0.0, 0.0, 0.0, 0.0};
            for (int d = 0; d < DDIM; ++d) {
                double xd = (double)xsh[d];
                float4 ev = *(const float4*)(e + (size_t)d * KCODE + k0);
                double t0 = xd - (double)ev.x; dd[0] = fma(t0, t0, dd[0]);
                double t1 = xd - (double)ev.y; dd[1] = fma(t1, t1, dd[1]);
                double t2 = xd - (double)ev.z; dd[2] = fma(t2, t2, dd[2]);
                double t3 = xd - (double)ev.w; dd[3] = fma(t3, t3, dd[3]);
            }
            double best = dd[0]; int bidx = k0;
            #pragma unroll
            for (int c = 1; c < 4; ++c)
                if (dd[c] < best) { best = dd[c]; bidx = k0 + c; }
            #pragma unroll
            for (int m = 1; m < 64; m <<= 1) {
                double ob = __shfl_xor(best, m);
                int    oi = __shfl_xor(bidx, m);
                if (ob < best || (ob == best && oi < bidx)) { best = ob; bidx = oi; }
            }
            if (lane == 0) { wbv[w] = best; wbi[w] = bidx; }
            __syncthreads();
            if (tid == 0) {
                double bb = wbv[0]; int bi = wbi[0];
                #pragma unroll
                for (int wv = 1; wv < 4; ++wv)
                    if (wbv[wv] < bb || (wbv[wv] == bb && wbi[wv] < bi)) {
                        bb = wbv[wv]; bi = wbi[wv];
                    }
                sidx[r] = bi; ps[r] = (float)bb;
            }
            __syncthreads();
        }
    }

    // ---- epilogue: one-hot fixup (vmcnt drained at the full __syncthreads),
    //      outq gather, indices, histogram, loss partial
    if (tid < 16) {
        const int idx = sidx[tid];
        encw[((size_t)tid << 10) + idx] = 1.0f;
        outidx[rowbase + tid] = (float)idx;
        atomicAdd(cnt + idx, 1);
    }
    {
        const int r = tid >> 4, c = tid & 15;
        const int idx = sidx[r];
        f32x4 ev = *(const f32x4*)(eT + (size_t)idx * DDIM + (c << 2));
        *((f32x4*)(outq + ((size_t)(rowbase + r) << 6)) + c) = ev;
    }
    if (tid == 64) {
        float s = 0.f;
        #pragma unroll
        for (int j = 0; j < 16; ++j) s += ps[j];
        partials[blockIdx.x] = s;
    }
}

// ---------------- k6: loss + perplexity ----------------
__global__ __launch_bounds__(256) void k6_scalar(const float* __restrict__ partials,
                                                 const int* __restrict__ cnt,
                                                 float* __restrict__ outloss,
                                                 float* __restrict__ outperp) {
    __shared__ double sd[256];
    const int tid = threadIdx.x;
    double s = 0.0;
    for (int i = tid; i < 8192; i += 256) s += (double)partials[i];
    sd[tid] = s;
    __syncthreads();
    for (int st = 128; st > 0; st >>= 1) {
        if (tid < st) sd[tid] += sd[tid + st];
        __syncthreads();
    }
    const double total = sd[0];
    __syncthreads();
    double h = 0.0;
    for (int k = tid; k < KCODE; k += 256) {
        double p = (double)cnt[k] / (double)NROWS;
        h -= p * log(p + 1e-10);
    }
    sd[tid] = h;
    __syncthreads();
    for (int st = 128; st > 0; st >>= 1) {
        if (tid < st) sd[tid] += sd[tid + st];
        __syncthreads();
    }
    if (tid == 0) {
        *outloss = (float)(total * 1.25 / (double)((long)NROWS * DDIM));
        *outperp = (float)exp(sd[0]);
    }
}

extern "C" void kernel_launch(void* const* d_in, const int* in_sizes, int n_in,
                              void* d_out, int out_size, void* d_ws, size_t ws_size,
                              hipStream_t stream) {
    const float* x = (const float*)d_in[0];       // [131072, 64]
    const float* e = (const float*)d_in[1];       // [64, 1024]
    float* out = (float*)d_out;

    float* ws_f = (float*)d_ws;
    float* enorm   = ws_f + WS_ENORM;
    float* eT      = ws_f + WS_ET;
    unsigned short* ebph = (unsigned short*)(ws_f + WS_EBPH);
    unsigned short* ebpl = (unsigned short*)(ws_f + WS_EBPL);
    int*   cnt     = (int*)(ws_f + WS_CNT);
    float* partials= ws_f + WS_PART;

    float* outq    = out + OFF_Q;
    float* outloss = out + OFF_LOSS;
    float* outperp = out + OFF_PERP;
    float* enc     = out + OFF_ENC;
    float* outidx  = out + OFF_IDX;
    float* dist    = out + OFF_DIST;

    hipLaunchKernelGGL(k1a_prep, dim3(4),    dim3(256), 0, stream, e, enorm, eT, cnt);
    hipLaunchKernelGGL(k1b_pack, dim3(64),   dim3(128), 0, stream, e, ebph, ebpl);
    hipLaunchKernelGGL(kA_fused, dim3(8192), dim3(256), 0, stream, x, e, ebph, ebpl, enorm,
                       eT, dist, enc, outq, outidx, cnt, partials);
    hipLaunchKernelGGL(k6_scalar,dim3(1),    dim3(256), 0, stream, partials, cnt, outloss, outperp);
}

// Round 14
// 283.987 us; speedup vs baseline: 1.8397x; 1.1283x over previous
//
#include <hip/hip_runtime.h>
#include <hip/hip_bf16.h>
#include <math.h>

// Problem constants
#define NROWS 131072      // 32*64*64
#define DDIM  64
#define KCODE 1024
#define TAU_B 0.008f      // split-bf16 dist err <= ~2e-3; 4x margin

// d_out layout (float elements, return order)
#define OFF_Q    0L
#define OFF_LOSS 8388608L
#define OFF_PERP 8388609L
#define OFF_ENC  8388610L                 // only 8B-aligned (base ≡ 2 mod 4 floats)
#define OFF_IDX  (OFF_ENC + 134217728L)   // 142606338
#define OFF_DIST (OFF_IDX + 131072L)      // 142737410 — only 8B-aligned

// ws layout (float elements)
#define WS_ENORM 0L          // 1024 f
#define WS_ET    1024L       // 65536 f   eT[k][d]
#define WS_EBPH  66560L      // 32768 f = 65536 ushort (packed B hi)
#define WS_EBPL  99328L      // 32768 f
#define WS_CNT   263168L     // 1024 int
#define WS_PART  395268L     // 8192 f

typedef short bf16x8 __attribute__((ext_vector_type(8)));
typedef float f32x4  __attribute__((ext_vector_type(4)));
typedef float f32x2  __attribute__((ext_vector_type(2)));
typedef _Float16 f16x4v __attribute__((ext_vector_type(4)));

__device__ inline unsigned short f2bf(float f) {
    unsigned u = __float_as_uint(f);
    unsigned r = (u + 0x7fffu + ((u >> 16) & 1u)) >> 16;
    return (unsigned short)r;
}
__device__ inline float bf2f(unsigned short h) {
    return __uint_as_float(((unsigned)h) << 16);
}
// f16 dist-tile swizzle: XOR bits 3,4 by row-group (i>>12 = row>>2).
// Preserves 8B (4 x f16) contiguity and alignment.
__device__ inline int dswz16(int i) { return i ^ (((i >> 12) & 3) << 3); }

// lgkmcnt-only barrier: LDS visibility without draining the vmem store queue
// (enc stores stay in flight across this boundary).
__device__ inline void lds_barrier() {
    asm volatile("s_waitcnt lgkmcnt(0)" ::: "memory");
    __builtin_amdgcn_s_barrier();
    __builtin_amdgcn_sched_barrier(0);
}

// ---------------- k1a: e-norms (f32), eT for gather, zero cnt ----------------
__global__ __launch_bounds__(256) void k1a_prep(const float* __restrict__ e,
                                                float* __restrict__ enorm,
                                                float* __restrict__ eT,
                                                int* __restrict__ cnt) {
    int k = blockIdx.x * 256 + threadIdx.x;   // grid=4 -> k in [0,1024)
    float s = 0.f;
    #pragma unroll 8
    for (int d = 0; d < DDIM; ++d) {
        float v = e[(size_t)d * KCODE + k];
        s = fmaf(v, v, s);
        eT[(size_t)k * DDIM + d] = v;
    }
    enorm[k] = s;
    cnt[k] = 0;
}

// ---------------- k1b: pack e into MFMA-B fragment layout, hi/lo bf16 ----------------
__global__ __launch_bounds__(128) void k1b_pack(const float* __restrict__ e,
                                                unsigned short* __restrict__ ebph,
                                                unsigned short* __restrict__ ebpl) {
    const int gct = blockIdx.x;          // 0..63
    const int ks  = threadIdx.x >> 6;    // 0..1
    const int l   = threadIdx.x & 63;
    const int col = (gct << 4) | (l & 15);
    const int kb  = (ks << 5) + ((l >> 4) << 3);
    const size_t ob = ((size_t)((gct << 1) | ks) * 64 + l) * 8;
    #pragma unroll
    for (int j = 0; j < 8; ++j) {
        float f = e[(size_t)(kb + j) * KCODE + col];
        unsigned short h = f2bf(f);
        float lo = f - bf2f(h);
        ebph[ob + j] = h;
        ebpl[ob + j] = f2bf(lo);
    }
}

// ---------------- kA: fused dist + enc(zero-stream interleaved in MFMA loop) ----------
// r11 structure (283us best) with ONE change: the first post-loop barrier is
// lgkm-only and the dist sweep runs immediately after it, so the sweep's
// stores enqueue while the enc stores drain. Full vmcnt drain happens at the
// single __syncthreads() before refine/one-hot fixup (correctness unchanged).
__global__ __launch_bounds__(256, 4) void kA_fused(const float* __restrict__ x,
                                                   const float* __restrict__ e,
                                                   const unsigned short* __restrict__ ebph,
                                                   const unsigned short* __restrict__ ebpl,
                                                   const float* __restrict__ enorm,
                                                   const float* __restrict__ eT,
                                                   float* __restrict__ dist,
                                                   float* __restrict__ enc,
                                                   float* __restrict__ outq,
                                                   float* __restrict__ outidx,
                                                   int* __restrict__ cnt,
                                                   float* __restrict__ partials) {
    __shared__ __align__(16) _Float16 dtH[16384];  // dist tile (f16), flat-2, swizzled
    __shared__ float hd[2];                        // flat 0,1 (row0 col0,1)
    __shared__ short xh[16 * 64];
    __shared__ short xl[16 * 64];
    __shared__ float xn[16];
    __shared__ float wm1[4][16], wm2[4][16];
    __shared__ int   wi1[4][16];
    __shared__ float ps[16];
    __shared__ int   sidx[16];
    __shared__ int   nearmask;
    __shared__ float xsh[DDIM];
    __shared__ double wbv[4];
    __shared__ int    wbi[4];

    const int tid  = threadIdx.x;
    const int lane = tid & 63;
    const int w    = tid >> 6;
    const int rowbase = blockIdx.x * 16;
    float* ebase = enc + ((size_t)blockIdx.x << 14);   // 16 rows x 1024, ≡2 mod 4

    // ---- stage x tile: f32 -> (hi,lo) bf16 in LDS; row norms via shuffle
    {
        if (tid == 0) nearmask = 0;
        float4 v = ((const float4*)(x + (size_t)rowbase * DDIM))[tid];
        int fi = tid * 4, r = fi >> 6, c = fi & 63;
        float fv[4] = {v.x, v.y, v.z, v.w};
        short hv[4], lv[4];
        #pragma unroll
        for (int q = 0; q < 4; ++q) {
            unsigned short hh = f2bf(fv[q]);
            hv[q] = (short)hh;
            lv[q] = (short)f2bf(fv[q] - bf2f(hh));
        }
        *(short4*)&xh[r * 64 + c] = make_short4(hv[0], hv[1], hv[2], hv[3]);
        *(short4*)&xl[r * 64 + c] = make_short4(lv[0], lv[1], lv[2], lv[3]);
        float s4 = fmaf(v.x, v.x, fmaf(v.y, v.y, fmaf(v.z, v.z, v.w * v.w)));
        #pragma unroll
        for (int m = 1; m < 16; m <<= 1) s4 += __shfl_xor(s4, m);
        if ((lane & 15) == 0) xn[r] = s4;   // r == tid>>4 for the 16 lanes of a row
    }
    __syncthreads();

    // ---- A fragments: lane l -> row=l&15, k=(l>>4)*8+j (+32 for second K-step)
    const int arow = lane & 15, akb = (lane >> 4) << 3;
    bf16x8 ah0 = *(const bf16x8*)&xh[arow * 64 + akb];
    bf16x8 ah1 = *(const bf16x8*)&xh[arow * 64 + 32 + akb];
    bf16x8 al0 = *(const bf16x8*)&xl[arow * 64 + akb];
    bf16x8 al1 = *(const bf16x8*)&xl[arow * 64 + 32 + akb];

    const int wr   = (lane >> 4) << 2;       // C-fragment row block (rows wr..wr+3)
    const int colb = (w << 8) | (lane & 15); // this lane's column (per ct: + ct*16)
    float xnv[4];
    #pragma unroll
    for (int r = 0; r < 4; ++r) xnv[r] = xn[wr + r];
    float env[16];
    #pragma unroll
    for (int ct = 0; ct < 16; ++ct) env[ct] = enorm[colb + (ct << 4)];  // L2-hot

    float m1[4], m2[4];
    int   i1[4];
    #pragma unroll
    for (int r = 0; r < 4; ++r) { m1[r] = 3.4e38f; m2[r] = 3.4e38f; i1[r] = 1 << 30; }

    const f32x4 z4 = {0.f, 0.f, 0.f, 0.f};

    #pragma unroll 4
    for (int ct = 0; ct < 16; ++ct) {
        const int gct = (w << 4) | ct;
        const size_t bo = ((size_t)(gct << 1) * 64 + lane) * 8;
        bf16x8 bh0 = *(const bf16x8*)(ebph + bo);
        bf16x8 bh1 = *(const bf16x8*)(ebph + bo + 512);
        bf16x8 bl0 = *(const bf16x8*)(ebpl + bo);
        bf16x8 bl1 = *(const bf16x8*)(ebpl + bo + 512);

        // interleaved enc zero-stream: one f32x4 per thread per ct (64KB/block total)
        {
            const int s = (ct << 8) + tid;          // 0..4095
            if (s < 4095) {
                *(f32x4*)(ebase + 2 + (s << 2)) = z4;
            } else {                                 // s == 4095: head + tail f32x2
                *(f32x2*)(ebase)         = (f32x2){0.f, 0.f};
                *(f32x2*)(ebase + 16382) = (f32x2){0.f, 0.f};
            }
        }

        f32x4 d = {0.f, 0.f, 0.f, 0.f};
        d = __builtin_amdgcn_mfma_f32_16x16x32_bf16(ah0, bh0, d, 0, 0, 0);
        d = __builtin_amdgcn_mfma_f32_16x16x32_bf16(ah1, bh1, d, 0, 0, 0);
        d = __builtin_amdgcn_mfma_f32_16x16x32_bf16(ah0, bl0, d, 0, 0, 0);
        d = __builtin_amdgcn_mfma_f32_16x16x32_bf16(ah1, bl1, d, 0, 0, 0);
        d = __builtin_amdgcn_mfma_f32_16x16x32_bf16(al0, bh0, d, 0, 0, 0);
        d = __builtin_amdgcn_mfma_f32_16x16x32_bf16(al1, bh1, d, 0, 0, 0);

        const int col = colb + (ct << 4);
        #pragma unroll
        for (int r = 0; r < 4; ++r) {
            float o = fmaf(-2.f, d[r], xnv[r] + env[ct]);
            if (o < m1[r]) { m2[r] = m1[r]; m1[r] = o; i1[r] = col; }
            else if (o < m2[r]) m2[r] = o;
            const int fl = ((wr + r) << 10) + col;
            if (fl >= 2) dtH[dswz16(fl - 2)] = (_Float16)o;
            else         hd[fl] = o;
        }
    }

    // ---- merge across the 16 lanes sharing each row group, tie -> lower index
    #pragma unroll
    for (int m = 1; m < 16; m <<= 1) {
        #pragma unroll
        for (int r = 0; r < 4; ++r) {
            float om1 = __shfl_xor(m1[r], m);
            int   oi1 = __shfl_xor(i1[r], m);
            float om2 = __shfl_xor(m2[r], m);
            if (om1 < m1[r] || (om1 == m1[r] && oi1 < i1[r])) {
                m2[r] = fminf(m1[r], om2); m1[r] = om1; i1[r] = oi1;
            } else {
                m2[r] = fminf(m2[r], om1);
            }
        }
    }
    if ((lane & 15) == 0) {
        #pragma unroll
        for (int r = 0; r < 4; ++r) {
            wm1[w][wr + r] = m1[r];
            wm2[w][wr + r] = m2[r];
            wi1[w][wr + r] = i1[r];
        }
    }

    // lgkm-only boundary: dtH + wm visible; enc stores remain in flight
    lds_barrier();

    // ---- dist sweep: flat contiguous f32x4 stores (issues while enc drains)
    {
        float* dbase = dist + ((size_t)rowbase << 10);   // ≡ 2 mod 4 floats
        #pragma unroll
        for (int j = 0; j < 16; ++j) {
            const int s = (j << 8) + tid;                // 0..4095
            if (s < 4095) {
                const int i0 = s << 2;
                const int iw = dswz16(i0);
                f16x4v h = *(const f16x4v*)&dtH[iw];
                f32x4 v = {(float)h[0], (float)h[1], (float)h[2], (float)h[3]};
                *(f32x4*)(dbase + 2 + i0) = v;
            }
        }
        if (tid == 255) {
            const int it = dswz16(16380);
            *(f32x2*)(dbase)         = (f32x2){hd[0], hd[1]};
            *(f32x2*)(dbase + 16382) = (f32x2){(float)dtH[it], (float)dtH[it + 1]};
        }
    }

    // ---- block argmin merge (wm visible since lds_barrier)
    if (tid < 16) {
        float bm1 = wm1[0][tid], bm2 = wm2[0][tid];
        int   bi  = wi1[0][tid];
        #pragma unroll
        for (int wv = 1; wv < 4; ++wv) {
            float om1 = wm1[wv][tid], om2 = wm2[wv][tid];
            int   oi  = wi1[wv][tid];
            if (om1 < bm1 || (om1 == bm1 && oi < bi)) {
                bm2 = fminf(bm1, om2); bm1 = om1; bi = oi;
            } else {
                bm2 = fminf(bm2, om1);
            }
        }
        sidx[tid] = bi;
        ps[tid]   = bm1;                    // min-dist == ||x-q||^2 for loss
        if (bm2 - bm1 < TAU_B) atomicOr(&nearmask, 1 << tid);
    }
    __syncthreads();   // FULL drain: all enc/dist stores landed; sidx/nearmask visible

    // ---- inline f64 refinement of near-tie rows (rare)
    if (nearmask) {
        for (int mrow = nearmask; mrow; mrow &= (mrow - 1)) {
            const int r = __ffs(mrow) - 1;
            if (tid < DDIM) xsh[tid] = x[(size_t)(rowbase + r) * DDIM + tid];
            __syncthreads();
            const int k0 = tid * 4;
            double dd[4] = {0.0, 0.0, 0.0, 0.0};
            for (int d = 0; d < DDIM; ++d) {
                double xd = (double)xsh[d];
                float4 ev = *(const float4*)(e + (size_t)d * KCODE + k0);
                double t0 = xd - (double)ev.x; dd[0] = fma(t0, t0, dd[0]);
                double t1 = xd - (double)ev.y; dd[1] = fma(t1, t1, dd[1]);
                double t2 = xd - (double)ev.z; dd[2] = fma(t2, t2, dd[2]);
                double t3 = xd - (double)ev.w; dd[3] = fma(t3, t3, dd[3]);
            }
            double best = dd[0]; int bidx = k0;
            #pragma unroll
            for (int c = 1; c < 4; ++c)
                if (dd[c] < best) { best = dd[c]; bidx = k0 + c; }
            #pragma unroll
            for (int m = 1; m < 64; m <<= 1) {
                double ob = __shfl_xor(best, m);
                int    oi = __shfl_xor(bidx, m);
                if (ob < best || (ob == best && oi < bidx)) { best = ob; bidx = oi; }
            }
            if (lane == 0) { wbv[w] = best; wbi[w] = bidx; }
            __syncthreads();
            if (tid == 0) {
                double bb = wbv[0]; int bi = wbi[0];
                #pragma unroll
                for (int wv = 1; wv < 4; ++wv)
                    if (wbv[wv] < bb || (wbv[wv] == bb && wbi[wv] < bi)) {
                        bb = wbv[wv]; bi = wbi[wv];
                    }
                sidx[r] = bi; ps[r] = (float)bb;
            }
            __syncthreads();
        }
    }

    // ---- epilogue: one-hot fixup (enc zeros drained at the full __syncthreads),
    //      outq gather, indices, histogram, loss partial
    if (tid < 16) {
        const int idx = sidx[tid];
        ebase[((size_t)tid << 10) + idx] = 1.0f;
        outidx[rowbase + tid] = (float)idx;
        atomicAdd(cnt + idx, 1);
    }
    {
        const int r = tid >> 4, c = tid & 15;
        const int idx = sidx[r];
        f32x4 ev = *(const f32x4*)(eT + (size_t)idx * DDIM + (c << 2));
        *((f32x4*)(outq + ((size_t)(rowbase + r) << 6)) + c) = ev;
    }
    if (tid == 64) {
        float s = 0.f;
        #pragma unroll
        for (int j = 0; j < 16; ++j) s += ps[j];
        partials[blockIdx.x] = s;
    }
}

// ---------------- k6: loss + perplexity ----------------
__global__ __launch_bounds__(256) void k6_scalar(const float* __restrict__ partials,
                                                 const int* __restrict__ cnt,
                                                 float* __restrict__ outloss,
                                                 float* __restrict__ outperp) {
    __shared__ double sd[256];
    const int tid = threadIdx.x;
    double s = 0.0;
    for (int i = tid; i < 8192; i += 256) s += (double)partials[i];
    sd[tid] = s;
    __syncthreads();
    for (int st = 128; st > 0; st >>= 1) {
        if (tid < st) sd[tid] += sd[tid + st];
        __syncthreads();
    }
    const double total = sd[0];
    __syncthreads();
    double h = 0.0;
    for (int k = tid; k < KCODE; k += 256) {
        double p = (double)cnt[k] / (double)NROWS;
        h -= p * log(p + 1e-10);
    }
    sd[tid] = h;
    __syncthreads();
    for (int st = 128; st > 0; st >>= 1) {
        if (tid < st) sd[tid] += sd[tid + st];
        __syncthreads();
    }
    if (tid == 0) {
        *outloss = (float)(total * 1.25 / (double)((long)NROWS * DDIM));
        *outperp = (float)exp(sd[0]);
    }
}

extern "C" void kernel_launch(void* const* d_in, const int* in_sizes, int n_in,
                              void* d_out, int out_size, void* d_ws, size_t ws_size,
                              hipStream_t stream) {
    const float* x = (const float*)d_in[0];       // [131072, 64]
    const float* e = (const float*)d_in[1];       // [64, 1024]
    float* out = (float*)d_out;

    float* ws_f = (float*)d_ws;
    float* enorm   = ws_f + WS_ENORM;
    float* eT      = ws_f + WS_ET;
    unsigned short* ebph = (unsigned short*)(ws_f + WS_EBPH);
    unsigned short* ebpl = (unsigned short*)(ws_f + WS_EBPL);
    int*   cnt     = (int*)(ws_f + WS_CNT);
    float* partials= ws_f + WS_PART;

    float* outq    = out + OFF_Q;
    float* outloss = out + OFF_LOSS;
    float* outperp = out + OFF_PERP;
    float* enc     = out + OFF_ENC;
    float* outidx  = out + OFF_IDX;
    float* dist    = out + OFF_DIST;

    hipLaunchKernelGGL(k1a_prep, dim3(4),    dim3(256), 0, stream, e, enorm, eT, cnt);
    hipLaunchKernelGGL(k1b_pack, dim3(64),   dim3(128), 0, stream, e, ebph, ebpl);
    hipLaunchKernelGGL(kA_fused, dim3(8192), dim3(256), 0, stream, x, e, ebph, ebpl, enorm,
                       eT, dist, enc, outq, outidx, cnt, partials);
    hipLaunchKernelGGL(k6_scalar,dim3(1),    dim3(256), 0, stream, partials, cnt, outloss, outperp);
}